// Round 19
// baseline (1220.716 us; speedup 1.0000x reference)
//
#include <hip/hip_runtime.h>

typedef unsigned short u16;
typedef short s16x8 __attribute__((ext_vector_type(8)));   // 8 bf16 bit-patterns
typedef float f32x4 __attribute__((ext_vector_type(4)));

#define DI __device__ __forceinline__

constexpr int N_ = 50000;
constexpr int E_ = 400000;
constexpr int G_ = 64;
constexpr int MS_ = 112;            // msg row stride in u16 (224 B)
constexpr int UVS_ = 608;           // UV row stride in f32: [U 0..299|pad|V 304..603|pad]

DI u16 f2bf(float f) {
    union { unsigned u; float f; } c; c.f = f;
    unsigned u = c.u;
    u += 0x7fffu + ((u >> 16) & 1u);   // RNE
    return (u16)(u >> 16);
}
DI float bf2f(u16 v) {
    union { unsigned u; float f; } c; c.u = (unsigned)v << 16;
    return c.f;
}
DI unsigned pkbf(float lo, float hi) {   // u32 = bf16(lo) | bf16(hi)<<16 (RNE)
    return (unsigned)f2bf(lo) | ((unsigned)f2bf(hi) << 16);
}

DI s16x8 ldv(const u16* p) { return *(const s16x8*)p; }
DI f32x4 MFMA(s16x8 a, s16x8 b, f32x4 c) {
    return __builtin_amdgcn_mfma_f32_16x16x32_bf16(a, b, c, 0, 0, 0);
}

// ---------------------------------------------------------------------------
// C-frag pair (transposed GEMM output: rows=channels, cols=edges) -> next
// GEMM's B-frag (lane&15=edge, k=kq*8+j), fused ReLU. 8 pkbf + 8
// ds_bpermute + 4 selects, no LDS storage. Verified vs C/D layout
// col=lane&15,row=kq*4+r (m89).
// ---------------------------------------------------------------------------
DI s16x8 conv_frag(const f32x4 a0, const f32x4 a1, int kq, int col) {
    unsigned c0 = pkbf(fmaxf(a0[0], 0.f), fmaxf(a0[1], 0.f));
    unsigned c1 = pkbf(fmaxf(a0[2], 0.f), fmaxf(a0[3], 0.f));
    unsigned c2 = pkbf(fmaxf(a1[0], 0.f), fmaxf(a1[1], 0.f));
    unsigned c3 = pkbf(fmaxf(a1[2], 0.f), fmaxf(a1[3], 0.f));
    int aA = (kq & 1) * 128 + col * 4;       // src lane (kq&1)*32 + col
    int aB = aA + 64;                        // src lane (kq&1)*32 + 16 + col
    unsigned A0 = __builtin_amdgcn_ds_bpermute(aA, (int)c0);
    unsigned A1 = __builtin_amdgcn_ds_bpermute(aA, (int)c1);
    unsigned A2 = __builtin_amdgcn_ds_bpermute(aA, (int)c2);
    unsigned A3 = __builtin_amdgcn_ds_bpermute(aA, (int)c3);
    unsigned B0 = __builtin_amdgcn_ds_bpermute(aB, (int)c0);
    unsigned B1 = __builtin_amdgcn_ds_bpermute(aB, (int)c1);
    unsigned B2 = __builtin_amdgcn_ds_bpermute(aB, (int)c2);
    unsigned B3 = __builtin_amdgcn_ds_bpermute(aB, (int)c3);
    bool hi = (kq >> 1) != 0;
    union { unsigned u[4]; s16x8 v; } o;
    o.u[0] = hi ? A2 : A0;
    o.u[1] = hi ? A3 : A1;
    o.u[2] = hi ? B2 : B0;
    o.u[3] = hi ? B3 : B1;
    return o.v;
}

// ---------------------------------------------------------------------------
// Named kernel: zero hist + repack weights f32 -> bf16 in MFMA-FRAGMENT-
// ORDER sections (elem (col,kq,j) at col*32+kq*8+j).
// GEMM1 hoisted to node level: H1 = relu([xi|xj-xi]@W1+b) =
// relu(U[dst]+V[src]) with U = A@(Wa-Wb)+b, V = A@Wb per NODE. wtu* hold
// W' = [Wa-Wb | 0pad | Wb | 0pad] (608 outputs) with bias in k-pad row
// (U half only). wt2/wt3 unchanged (bias in k=300 row).
// ---------------------------------------------------------------------------
__global__ __launch_bounds__(256)
void ModelGNN_35304631174019_kernel(
          const float* __restrict__ l0w1, const float* __restrict__ l0w2,
          const float* __restrict__ l0w3, const float* __restrict__ l1w1,
          const float* __restrict__ l1w2, const float* __restrict__ l1w3,
          const float* __restrict__ l0b1, const float* __restrict__ l0b2,
          const float* __restrict__ l0b3, const float* __restrict__ l1b1,
          const float* __restrict__ l1b2, const float* __restrict__ l1b3,
          float4* __restrict__ histz,
          u16* __restrict__ wtu0, u16* __restrict__ wtu1,
          u16* __restrict__ wt2a, u16* __restrict__ wt2b,
          u16* __restrict__ wt3a, u16* __restrict__ wt3b)
{
    int i = blockIdx.x * 256 + threadIdx.x;
    if (i < 12500) { histz[i] = make_float4(0.f, 0.f, 0.f, 0.f); return; }
    int f = i - 12500;

    if (f < 19456) {                       // wtu0: layer1 node W' [608 out][32 k]
        int sec = f >> 9, w = f & 511;
        int col = w >> 5, kq = (w & 31) >> 3, j = w & 7;
        int chunk = sec >> 1, b01 = sec & 1;
        int n = chunk * 32 + b01 * 16 + col;
        int k = kq * 8 + j;
        u16 v = 0;
        if (k < 7) {
            if (n < 300)                  v = f2bf(l0w1[k * 300 + n] - l0w1[(7 + k) * 300 + n]);
            else if (n >= 304 && n < 604) v = f2bf(l0w1[(7 + k) * 300 + (n - 304)]);
        } else if (k == 7) {
            if (n < 300) v = f2bf(l0b1[n]);
        }
        wtu0[f] = v; return;
    }
    f -= 19456;
    if (f < 77824) {                       // wtu1: layer2 node W' [608 out][128 k]
        int sec = f >> 9, w = f & 511;
        int col = w >> 5, kq = (w & 31) >> 3, j = w & 7;
        int chunk = sec >> 3, r = sec & 7, s = r >> 1, b01 = r & 1;
        int n = chunk * 32 + b01 * 16 + col;
        int k = s * 32 + kq * 8 + j;
        u16 v = 0;
        if (k < 100) {
            if (n < 300)                  v = f2bf(l1w1[k * 300 + n] - l1w1[(100 + k) * 300 + n]);
            else if (n >= 304 && n < 604) v = f2bf(l1w1[(100 + k) * 300 + (n - 304)]);
        } else if (k == 100) {
            if (n < 300) v = f2bf(l1b1[n]);
        }
        wtu1[f] = v; return;
    }
    f -= 77824;
    if (f < 204800) {                      // wt2a / wt2b: 300x300, K=320 (KA=10)
        const float* src = (f < 102400) ? l0w2 : l1w2;
        const float* bia = (f < 102400) ? l0b2 : l1b2;
        u16* dst = (f < 102400) ? wt2a : wt2b;
        int f2 = (f < 102400) ? f : f - 102400;
        int sec = f2 >> 9, w = f2 & 511;
        int col = w >> 5, rem = w & 31;
        int n0c = sec / 20, r = sec % 20;
        int s = r >> 1, b01 = r & 1;
        int n = n0c * 32 + b01 * 16 + col, k = s * 32 + rem;
        u16 v = 0;
        if (n < 300) {
            if (k < 300)       v = f2bf(src[k * 300 + n]);
            else if (k == 300) v = f2bf(bia[n]);
        }
        dst[f2] = v;
        return;
    }
    f -= 204800;
    if (f < 71680) {                       // wt3a / wt3b: 300x100 -> [112 n3][320 k]
        const float* src = (f < 35840) ? l0w3 : l1w3;
        const float* bia = (f < 35840) ? l0b3 : l1b3;
        u16* dst = (f < 35840) ? wt3a : wt3b;
        int f2 = (f < 35840) ? f : f - 35840;
        int sec = f2 >> 9, w = f2 & 511;
        int col = w >> 5, rem = w & 31;
        int ch = sec / 7, u = sec % 7;
        int n3 = u * 16 + col, k = ch * 32 + rem;
        u16 v = 0;
        if (n3 < 100) {
            if (k < 300)       v = f2bf(src[k * 100 + n3]);
            else if (k == 300) v = f2bf(bia[n3]);
        }
        dst[f2] = v;
        return;
    }
}

// ---------------------------------------------------------------------------
// Count-sort edges by dst: hist -> exclusive scan -> scatter-fill.
// pos[d] = run END after fill (start = pos[d-1] or 0) -- used by reduce_k.
// ---------------------------------------------------------------------------
__global__ __launch_bounds__(256)
void hist_k(const int* __restrict__ ei, int* __restrict__ hist)
{
    int i = blockIdx.x * 256 + threadIdx.x;
    if (i < E_) atomicAdd(&hist[ei[E_ + i]], 1);
}

__global__ __launch_bounds__(1024)
void scan_k(int* h)   // in-place exclusive scan of h[50000], single block
{
    __shared__ int part[1024];
    const int t = threadIdx.x;
    const int CH = 49;
    int base = t * CH;
    int end = base + CH; if (end > 50000) end = 50000;
    int s = 0;
    for (int i = base; i < end; ++i) s += h[i];
    part[t] = s;
    __syncthreads();
    for (int d = 1; d < 1024; d <<= 1) {
        int v = (t >= d) ? part[t - d] : 0;
        __syncthreads();
        part[t] += v;
        __syncthreads();
    }
    int run = (t ? part[t - 1] : 0);
    for (int i = base; i < end; ++i) { int c = h[i]; h[i] = run; run += c; }
}

__global__ __launch_bounds__(256)
void fill_k(const int* __restrict__ ei, int* __restrict__ pos, int* __restrict__ sei)
{
    int i = blockIdx.x * 256 + threadIdx.x;
    if (i >= E_) return;
    int s = ei[i], d = ei[E_ + i];
    int p = atomicAdd(&pos[d], 1);
    sei[p] = s; sei[E_ + p] = d;
}

// ---------------------------------------------------------------------------
// gemm_uv: per-node GEMM  UV[n] = [A_n|1] @ W'  (608 outputs, f32 out).
// KA=1: A=x (stride 7, bias k=7). KA=4: A=agg0 (stride 100, bias k=100).
// Wave = 32 nodes (2 x 16-row tiles); 19 output chunks of 32; transposed
// MFMA output goes through a 4KB wave-private LDS transit to produce
// row-major UV (coalesced 128B row stores).
// ---------------------------------------------------------------------------
template<int KA>
__global__ __launch_bounds__(256, 2)
void gemm_uv(const float* __restrict__ A, const u16* __restrict__ W,
             float* __restrict__ UV)
{
    __shared__ __align__(16) float SC[4][1024];       // 4KB per wave
    const int tid = threadIdx.x, wave = tid >> 6, lane = tid & 63;
    const int col = lane & 15, kq = lane >> 4;
    const int nb = blockIdx.x * 128 + wave * 32;
    const int fragoff = col * 32 + kq * 8;

    s16x8 aF[2][KA];
    #pragma unroll
    for (int rt = 0; rt < 2; ++rt) {
        int node = nb + rt * 16 + col; if (node >= N_) node = N_ - 1;
        if constexpr (KA == 1) {
            s16x8 t = {0, 0, 0, 0, 0, 0, 0, 0};
            if (kq == 0) {
                const float* r = A + (size_t)node * 7;
                #pragma unroll
                for (int j = 0; j < 7; ++j) t[j] = (short)f2bf(r[j]);
                t[7] = (short)0x3f80;                 // bias slot k=7
            }
            aF[rt][0] = t;
        } else {
            const float* r = A + (size_t)node * 100;
            #pragma unroll
            for (int s = 0; s < KA; ++s) {
                int k0 = s * 32 + kq * 8;
                s16x8 t = {0, 0, 0, 0, 0, 0, 0, 0};
                if (k0 + 8 <= 100) {
                    float4 a = *(const float4*)(r + k0);
                    float4 b = *(const float4*)(r + k0 + 4);
                    t[0] = (short)f2bf(a.x); t[1] = (short)f2bf(a.y);
                    t[2] = (short)f2bf(a.z); t[3] = (short)f2bf(a.w);
                    t[4] = (short)f2bf(b.x); t[5] = (short)f2bf(b.y);
                    t[6] = (short)f2bf(b.z); t[7] = (short)f2bf(b.w);
                } else if (k0 == 96) {
                    float4 a = *(const float4*)(r + 96);
                    t[0] = (short)f2bf(a.x); t[1] = (short)f2bf(a.y);
                    t[2] = (short)f2bf(a.z); t[3] = (short)f2bf(a.w);
                    t[4] = (short)0x3f80;             // bias slot k=100
                }
                aF[rt][s] = t;
            }
        }
    }

    float* SCw = SC[wave];
    #pragma unroll 1
    for (int c = 0; c < 19; ++c) {
        const u16* w0 = W + (size_t)(c * 2 * KA) * 512 + fragoff;
        s16x8 wb[2 * KA];
        #pragma unroll
        for (int t = 0; t < 2 * KA; ++t) wb[t] = ldv(w0 + t * 512);
        f32x4 z = {0.f, 0.f, 0.f, 0.f};
        f32x4 ac[2][2] = {{z, z}, {z, z}};            // [b01][rt]
        #pragma unroll
        for (int s = 0; s < KA; ++s)
            #pragma unroll
            for (int rt = 0; rt < 2; ++rt) {
                ac[0][rt] = MFMA(wb[2 * s],     aF[rt][s], ac[0][rt]);
                ac[1][rt] = MFMA(wb[2 * s + 1], aF[rt][s], ac[1][rt]);
            }
        // transit: ch-major frag -> node-major rows (wave-private, lgkm order)
        #pragma unroll
        for (int cb = 0; cb < 2; ++cb)
            #pragma unroll
            for (int rt = 0; rt < 2; ++rt)
                #pragma unroll
                for (int r = 0; r < 4; ++r)
                    SCw[(rt * 16 + col) * 32 + cb * 16 + kq * 4 + r] = ac[cb][rt][r];
        #pragma unroll
        for (int p = 0; p < 4; ++p) {
            int row = p * 8 + (lane >> 3);
            int node = nb + row;
            if (node < N_) {
                float4 v = *(const float4*)(SCw + row * 32 + (lane & 7) * 4);
                *(float4*)(UV + (size_t)node * UVS_ + c * 32 + (lane & 7) * 4) = v;
            }
        }
    }
}

// per-chunk GEMM2+GEMM3 compute from named register arrays
#define COMPUTE2(W2R, W3R, CH) {                                              \
    f32x4 z_ = {0.f, 0.f, 0.f, 0.f};                                          \
    f32x4 ac_[2][2] = {{z_, z_}, {z_, z_}};                                   \
    _Pragma("unroll")                                                         \
    for (int s_ = 0; s_ < 10; ++s_) {                                         \
        _Pragma("unroll")                                                     \
        for (int rt_ = 0; rt_ < 2; ++rt_) {                                   \
            ac_[0][rt_] = MFMA(W2R[2 * s_],     a2[rt_][s_], ac_[0][rt_]);    \
            ac_[1][rt_] = MFMA(W2R[2 * s_ + 1], a2[rt_][s_], ac_[1][rt_]);    \
        }                                                                     \
    }                                                                         \
    s16x8 a3_[2];                                                             \
    _Pragma("unroll")                                                         \
    for (int rt_ = 0; rt_ < 2; ++rt_)                                         \
        a3_[rt_] = conv_frag(ac_[0][rt_], ac_[1][rt_], kq, col);              \
    if ((CH) == 9 && kq == 1) {                                               \
        a3_[0][4] = (short)0x3f80;                                            \
        a3_[1][4] = (short)0x3f80;                                            \
    }                                                                         \
    _Pragma("unroll")                                                         \
    for (int u_ = 0; u_ < 7; ++u_) {                                          \
        mac[0][u_] = MFMA(W3R[u_], a3_[0], mac[0][u_]);                       \
        mac[1][u_] = MFMA(W3R[u_], a3_[1], mac[1][u_]);                       \
    }                                                                         \
}

// ---------------------------------------------------------------------------
// edge_uv R19: per-edge H1 = relu(U[dst]+V[src]) -> GEMM2+GEMM3 -> msg.
// R18 post-mortem: ping-pong prefetch (216 transient VGPR) pinned the
// kernel at 1 wave/SIMD (occ 10.5%) and its latency-hiding no longer pays
// now that GEMM1 is hoisted (R16 A/B: batch-only @2w/SIMD 436 beat
// ping-pong @1w/SIMD 440 on MORE work). This round: R16-style per-chunk
// static batches (w2[20] before MFMAs, w3[7] before conv_frag), capped
// __launch_bounds__(256,2) -> <=256 unified regs -> 2 waves/SIMD.
// Spill guard: WRITE_SIZE must stay ~111 MB.
// ---------------------------------------------------------------------------
__global__ __launch_bounds__(256, 2)
void edge_uv(const float* __restrict__ UV, const int* __restrict__ ei,
             const u16* __restrict__ W2, const u16* __restrict__ W3,
             u16* __restrict__ msg)
{
    __shared__ __align__(16) u16 SCR[4 * 32 * MS_];   // 28,672 B (epilogue)

    const int tid  = threadIdx.x;
    const int wave = tid >> 6, lane = tid & 63;
    const int col  = lane & 15, kq = lane >> 4;
    const int ebase = blockIdx.x * 128 + wave * 32;   // 32 edges per wave
    const int fragoff = col * 32 + kq * 8;            // in-section lane offset

    u16* SCw = SCR + wave * (32 * MS_);

    // ---- build a2 fragments from U[dst]+V[src] (fused add+relu+pack) ----
    s16x8 a2[2][10];
    #pragma unroll
    for (int rt = 0; rt < 2; ++rt) {
        const int e = ebase + rt * 16 + col;
        const int dn = ei[E_ + e];                    // x_i (dst)
        const int sn = ei[e];                         // x_j (src)
        const float* Ud = UV + (size_t)dn * UVS_;
        const float* Vs = UV + (size_t)sn * UVS_ + 304;
        #pragma unroll
        for (int h = 0; h < 2; ++h) {                 // two 5-chunk halves
            float4 ua[5], ub[5], va[5], vb[5];
            #pragma unroll
            for (int q = 0; q < 5; ++q) {
                int k0 = (h * 5 + q) * 32 + kq * 8;
                const float4 zz = make_float4(0.f, 0.f, 0.f, 0.f);
                bool ok = (k0 <= 296);                // slices beyond 304 are 0
                ua[q] = ok ? *(const float4*)(Ud + k0)     : zz;
                ub[q] = ok ? *(const float4*)(Ud + k0 + 4) : zz;
                va[q] = ok ? *(const float4*)(Vs + k0)     : zz;
                vb[q] = ok ? *(const float4*)(Vs + k0 + 4) : zz;
            }
            #pragma unroll
            for (int q = 0; q < 5; ++q) {
                unsigned p0 = pkbf(fmaxf(ua[q].x + va[q].x, 0.f),
                                   fmaxf(ua[q].y + va[q].y, 0.f));
                unsigned p1 = pkbf(fmaxf(ua[q].z + va[q].z, 0.f),
                                   fmaxf(ua[q].w + va[q].w, 0.f));
                unsigned p2 = pkbf(fmaxf(ub[q].x + vb[q].x, 0.f),
                                   fmaxf(ub[q].y + vb[q].y, 0.f));
                unsigned p3 = pkbf(fmaxf(ub[q].z + vb[q].z, 0.f),
                                   fmaxf(ub[q].w + vb[q].w, 0.f));
                union { unsigned u[4]; s16x8 v; } o;
                o.u[0] = p0; o.u[1] = p1; o.u[2] = p2; o.u[3] = p3;
                a2[rt][h * 5 + q] = o.v;
            }
        }
    }
    if (kq == 1) {                                    // GEMM2 k=300 bias slot
        a2[0][9][4] = (short)0x3f80;
        a2[1][9][4] = (short)0x3f80;
    }

    f32x4 mac[2][7];
    #pragma unroll
    for (int rt = 0; rt < 2; ++rt)
        #pragma unroll
        for (int u = 0; u < 7; ++u) { f32x4 z = {0.f, 0.f, 0.f, 0.f}; mac[rt][u] = z; }

    // ---- GEMM2 (K=320) fused with GEMM3, per-chunk static batches ----
    #pragma unroll 1
    for (int ch = 0; ch < 10; ++ch) {
        const u16* w0 = W2 + (size_t)(ch * 20) * 512 + fragoff;
        s16x8 wb[20];                                 // batched chunk loads
        #pragma unroll
        for (int s = 0; s < 20; ++s) wb[s] = ldv(w0 + s * 512);
        f32x4 z = {0.f, 0.f, 0.f, 0.f};
        f32x4 ac[2][2] = {{z, z}, {z, z}};
        #pragma unroll
        for (int s = 0; s < 10; ++s)
            #pragma unroll
            for (int rt = 0; rt < 2; ++rt) {
                ac[0][rt] = MFMA(wb[2 * s],     a2[rt][s], ac[0][rt]);
                ac[1][rt] = MFMA(wb[2 * s + 1], a2[rt][s], ac[1][rt]);
            }
        // issue W3 loads before conv_frag (overlap bpermute latency)
        s16x8 w3b[7];
        #pragma unroll
        for (int u = 0; u < 7; ++u)
            w3b[u] = ldv(W3 + (size_t)(ch * 7 + u) * 512 + fragoff);
        s16x8 a3[2];
        #pragma unroll
        for (int rt = 0; rt < 2; ++rt)
            a3[rt] = conv_frag(ac[0][rt], ac[1][rt], kq, col);
        if (ch == 9 && kq == 1) {                     // GEMM3 k=300 bias slot
            a3[0][4] = (short)0x3f80;
            a3[1][4] = (short)0x3f80;
        }
        #pragma unroll
        for (int u = 0; u < 7; ++u) {
            mac[0][u] = MFMA(w3b[u], a3[0], mac[0][u]);
            mac[1][u] = MFMA(w3b[u], a3[1], mac[1][u]);
        }
    }

    // ---- epilogue: mac rows=out-channels, cols=edges. Pack relu'd pairs to
    //      LDS [32 edges][112 ch], then coalesced 16B-lane global stores ----
    #pragma unroll
    for (int rt = 0; rt < 2; ++rt) {
        const int row = rt * 16 + col;
        #pragma unroll
        for (int u = 0; u < 7; ++u) {
            unsigned p0 = pkbf(fmaxf(mac[rt][u][0], 0.f), fmaxf(mac[rt][u][1], 0.f));
            unsigned p1 = pkbf(fmaxf(mac[rt][u][2], 0.f), fmaxf(mac[rt][u][3], 0.f));
            int chb = u * 16 + kq * 4;
            *(unsigned*)(SCw + row * MS_ + chb)     = p0;
            *(unsigned*)(SCw + row * MS_ + chb + 2) = p1;
        }
    }
    // wave-private region: lgkmcnt ordering only
    u16* gdst = msg + (size_t)ebase * MS_;
    #pragma unroll
    for (int q2 = 0; q2 < 7; ++q2) {
        s16x8 v = ldv(SCw + q2 * 512 + lane * 8);
        *(s16x8*)(gdst + q2 * 512 + lane * 8) = v;
    }
}

// ---------------------------------------------------------------------------
// reduce_k: segment-max over sorted msg runs (stride MS_). One wave per node.
// Writes EVERY node (empty run -> 0), so agg needs no zero-init.
// ---------------------------------------------------------------------------
__global__ __launch_bounds__(256)
void reduce_k(const u16* __restrict__ msg, const int* __restrict__ pos,
              float* __restrict__ agg)
{
    const int n = blockIdx.x * 4 + (threadIdx.x >> 6);
    if (n >= N_) return;
    const int lane = threadIdx.x & 63;
    const int start = n ? pos[n - 1] : 0;
    const int end   = pos[n];
    float m0 = 0.f, m1 = 0.f;
    for (int e = start; e < end; ++e) {
        const u16* row = msg + (size_t)e * MS_;
        m0 = fmaxf(m0, bf2f(row[lane]));
        if (lane < 36) m1 = fmaxf(m1, bf2f(row[64 + lane]));
    }
    agg[(size_t)n * 100 + lane] = m0;
    if (lane < 36) agg[(size_t)n * 100 + 64 + lane] = m1;
}

// ---------------------------------------------------------------------------
// pool: one block per graph (batch sorted -> binary-search bounds).
// ---------------------------------------------------------------------------
__global__ __launch_bounds__(256)
void pool(const float* __restrict__ agg1, const int* __restrict__ batch,
          const float* __restrict__ u, float* __restrict__ pooled)
{
    const int g = blockIdx.x;
    int lo = 0, hi = N_;
    while (lo < hi) { int mid = (lo + hi) >> 1; if (batch[mid] < g) lo = mid + 1; else hi = mid; }
    const int start = lo;
    int lo2 = start, hi2 = N_;
    while (lo2 < hi2) { int mid = (lo2 + hi2) >> 1; if (batch[mid] < g + 1) lo2 = mid + 1; else hi2 = mid; }
    const int end = lo2;

    const int c = threadIdx.x & 127, half = threadIdx.x >> 7;
    float sm = 0.f, mx = 0.f;
    if (c < 100)
        for (int n = start + half; n < end; n += 2) {
            float v = agg1[(size_t)n * 100 + c];
            sm += v; mx = fmaxf(mx, v);
        }
    __shared__ float ssum[128], smax[128];
    if (half) { ssum[c] = sm; smax[c] = mx; }
    __syncthreads();
    if (!half && c < 100) {
        sm += ssum[c]; mx = fmaxf(mx, smax[c]);
        int cnt = end - start;
        pooled[g * 302 + c]       = sm;
        pooled[g * 302 + 100 + c] = sm / fmaxf((float)cnt, 1.f);
        pooled[g * 302 + 200 + c] = mx;
    }
    if (threadIdx.x == 0) {
        pooled[g * 302 + 300] = u[g * 2];
        pooled[g * 302 + 301] = u[g * 2 + 1];
    }
}

// ---------------------------------------------------------------------------
// final 302 -> 100 -> 100 -> 2 MLP, one block per graph, fp32
// ---------------------------------------------------------------------------
__global__ __launch_bounds__(128)
void final_mlp(const float* __restrict__ pooled,
               const float* __restrict__ w1, const float* __restrict__ b1,
               const float* __restrict__ w2, const float* __restrict__ b2,
               const float* __restrict__ w3, const float* __restrict__ b3,
               float* __restrict__ out)
{
    const int g = blockIdx.x, t = threadIdx.x;
    __shared__ float P[302], T1[100], T2[100];
    for (int i = t; i < 302; i += 128) P[i] = pooled[g * 302 + i];
    __syncthreads();
    if (t < 100) {
        float a = b1[t];
        for (int i = 0; i < 302; ++i) a = fmaf(P[i], w1[i * 100 + t], a);
        T1[t] = fmaxf(a, 0.f);
    }
    __syncthreads();
    if (t < 100) {
        float a = b2[t];
        for (int i = 0; i < 100; ++i) a = fmaf(T1[i], w2[i * 100 + t], a);
        T2[t] = fmaxf(a, 0.f);
    }
    __syncthreads();
    if (t < 2) {
        float a = b3[t];
        for (int i = 0; i < 100; ++i) a = fmaf(T2[i], w3[i * 2 + t], a);
        out[g * 2 + t] = a;
    }
}

// ---------------------------------------------------------------------------
extern "C" void kernel_launch(void* const* d_in, const int* in_sizes, int n_in,
                              void* d_out, int out_size, void* d_ws, size_t ws_size,
                              hipStream_t stream)
{
    const float* x     = (const float*)d_in[0];
    const int*   ei    = (const int*)d_in[1];
    const int*   batch = (const int*)d_in[2];
    const float* uu    = (const float*)d_in[3];
    const float *l0w1 = (const float*)d_in[4],  *l0b1 = (const float*)d_in[5];
    const float *l0w2 = (const float*)d_in[6],  *l0b2 = (const float*)d_in[7];
    const float *l0w3 = (const float*)d_in[8],  *l0b3 = (const float*)d_in[9];
    const float *l1w1 = (const float*)d_in[10], *l1b1 = (const float*)d_in[11];
    const float *l1w2 = (const float*)d_in[12], *l1b2 = (const float*)d_in[13];
    const float *l1w3 = (const float*)d_in[14], *l1b3 = (const float*)d_in[15];
    const float *lw1  = (const float*)d_in[16], *lb1  = (const float*)d_in[17];
    const float *lw2  = (const float*)d_in[18], *lb2  = (const float*)d_in[19];
    const float *lw3  = (const float*)d_in[20], *lb3  = (const float*)d_in[21];

    char* w = (char*)d_ws;
    float* agg0   = (float*)(w);                    //  20,000,000 B
    float* agg1   = (float*)(w + 20000000);         //  20,000,000 B
    float* pooled = (float*)(w + 40000000);         //      77,312 B
    u16* wtu0 = (u16*)(w + 40077312);               //      38,912 B
    u16* wtu1 = (u16*)(w + 40116224);               //     155,648 B
    u16* wt2a = (u16*)(w + 40271872);               //     204,800 B
    u16* wt2b = (u16*)(w + 40476672);               //     204,800 B
    u16* wt3a = (u16*)(w + 40681472);               //      71,680 B
    u16* wt3b = (u16*)(w + 40753152);               //      71,680 B
    int* hist = (int*)(w + 40824832);               //     200,000 B (run ends)
    int* sei  = (int*)(w + 41024832);               //   3,200,000 B (sorted)
    u16* msg  = (u16*)(w + 44224832);               //  89,600,000 B (224B rows)
    float* UV = (float*)(w + 133824832);            // 121,600,000 B (N x 608 f32)
                                                    // total ~243.6 MiB

    ModelGNN_35304631174019_kernel<<<1509, 256, 0, stream>>>(
        l0w1, l0w2, l0w3, l1w1, l1w2, l1w3,
        l0b1, l0b2, l0b3, l1b1, l1b2, l1b3,
        (float4*)hist, wtu0, wtu1, wt2a, wt2b, wt3a, wt3b);
    hist_k<<<1563, 256, 0, stream>>>(ei, hist);
    scan_k<<<1, 1024, 0, stream>>>(hist);
    fill_k<<<1563, 256, 0, stream>>>(ei, hist, sei);
    gemm_uv<1><<<391, 256, 0, stream>>>(x, wtu0, UV);
    edge_uv<<<3125, 256, 0, stream>>>(UV, sei, wt2a, wt3a, msg);
    reduce_k<<<12500, 256, 0, stream>>>(msg, hist, agg0);
    gemm_uv<4><<<391, 256, 0, stream>>>(agg0, wtu1, UV);
    edge_uv<<<3125, 256, 0, stream>>>(UV, sei, wt2b, wt3b, msg);
    reduce_k<<<12500, 256, 0, stream>>>(msg, hist, agg1);
    pool<<<G_, 256, 0, stream>>>(agg1, batch, uu, pooled);
    final_mlp<<<G_, 128, 0, stream>>>(pooled, lw1, lb1, lw2, lb2, lw3, lb3, (float*)d_out);
}

// Round 20
// 1080.800 us; speedup vs baseline: 1.1295x; 1.1295x over previous
//
#include <hip/hip_runtime.h>

typedef unsigned short u16;
typedef short s16x8 __attribute__((ext_vector_type(8)));   // 8 bf16 bit-patterns
typedef float f32x4 __attribute__((ext_vector_type(4)));

#define DI __device__ __forceinline__

constexpr int N_ = 50000;
constexpr int E_ = 400000;
constexpr int G_ = 64;
constexpr int MS_ = 112;            // msg row stride in u16 (224 B)
constexpr int US_ = 304;            // U row stride in f32 (300 used + pad)
constexpr int VS_ = 304;            // V row stride in u16 bf16 (300 used + pad)

DI u16 f2bf(float f) {
    union { unsigned u; float f; } c; c.f = f;
    unsigned u = c.u;
    u += 0x7fffu + ((u >> 16) & 1u);   // RNE
    return (u16)(u >> 16);
}
DI float bf2f(u16 v) {
    union { unsigned u; float f; } c; c.u = (unsigned)v << 16;
    return c.f;
}
DI unsigned pkbf(float lo, float hi) {   // u32 = bf16(lo) | bf16(hi)<<16 (RNE)
    return (unsigned)f2bf(lo) | ((unsigned)f2bf(hi) << 16);
}

DI s16x8 ldv(const u16* p) { return *(const s16x8*)p; }
DI f32x4 MFMA(s16x8 a, s16x8 b, f32x4 c) {
    return __builtin_amdgcn_mfma_f32_16x16x32_bf16(a, b, c, 0, 0, 0);
}

// ---------------------------------------------------------------------------
// C-frag pair (transposed GEMM output: rows=channels, cols=edges) -> next
// GEMM's B-frag (lane&15=edge, k=kq*8+j), fused ReLU. 8 pkbf + 8
// ds_bpermute + 4 selects, no LDS storage. Verified vs C/D layout
// col=lane&15,row=kq*4+r (m89).
// ---------------------------------------------------------------------------
DI s16x8 conv_frag(const f32x4 a0, const f32x4 a1, int kq, int col) {
    unsigned c0 = pkbf(fmaxf(a0[0], 0.f), fmaxf(a0[1], 0.f));
    unsigned c1 = pkbf(fmaxf(a0[2], 0.f), fmaxf(a0[3], 0.f));
    unsigned c2 = pkbf(fmaxf(a1[0], 0.f), fmaxf(a1[1], 0.f));
    unsigned c3 = pkbf(fmaxf(a1[2], 0.f), fmaxf(a1[3], 0.f));
    int aA = (kq & 1) * 128 + col * 4;       // src lane (kq&1)*32 + col
    int aB = aA + 64;                        // src lane (kq&1)*32 + 16 + col
    unsigned A0 = __builtin_amdgcn_ds_bpermute(aA, (int)c0);
    unsigned A1 = __builtin_amdgcn_ds_bpermute(aA, (int)c1);
    unsigned A2 = __builtin_amdgcn_ds_bpermute(aA, (int)c2);
    unsigned A3 = __builtin_amdgcn_ds_bpermute(aA, (int)c3);
    unsigned B0 = __builtin_amdgcn_ds_bpermute(aB, (int)c0);
    unsigned B1 = __builtin_amdgcn_ds_bpermute(aB, (int)c1);
    unsigned B2 = __builtin_amdgcn_ds_bpermute(aB, (int)c2);
    unsigned B3 = __builtin_amdgcn_ds_bpermute(aB, (int)c3);
    bool hi = (kq >> 1) != 0;
    union { unsigned u[4]; s16x8 v; } o;
    o.u[0] = hi ? A2 : A0;
    o.u[1] = hi ? A3 : A1;
    o.u[2] = hi ? B2 : B0;
    o.u[3] = hi ? B3 : B1;
    return o.v;
}

// ---------------------------------------------------------------------------
// Named kernel: zero hist + repack weights f32 -> bf16 in MFMA-FRAGMENT-
// ORDER sections (elem (col,kq,j) at col*32+kq*8+j).
// GEMM1 hoisted to node level: H1 = relu([xi|xj-xi]@W1+b) =
// relu(U[dst]+V[src]) with U = A@(Wa-Wb)+b, V = A@Wb per NODE. wtu* hold
// W' = [Wa-Wb | 0pad | Wb | 0pad] (608 outputs) with bias in k-pad row
// (U half only). wt2/wt3 unchanged (bias in k=300 row).
// ---------------------------------------------------------------------------
__global__ __launch_bounds__(256)
void ModelGNN_35304631174019_kernel(
          const float* __restrict__ l0w1, const float* __restrict__ l0w2,
          const float* __restrict__ l0w3, const float* __restrict__ l1w1,
          const float* __restrict__ l1w2, const float* __restrict__ l1w3,
          const float* __restrict__ l0b1, const float* __restrict__ l0b2,
          const float* __restrict__ l0b3, const float* __restrict__ l1b1,
          const float* __restrict__ l1b2, const float* __restrict__ l1b3,
          float4* __restrict__ histz,
          u16* __restrict__ wtu0, u16* __restrict__ wtu1,
          u16* __restrict__ wt2a, u16* __restrict__ wt2b,
          u16* __restrict__ wt3a, u16* __restrict__ wt3b)
{
    int i = blockIdx.x * 256 + threadIdx.x;
    if (i < 12500) { histz[i] = make_float4(0.f, 0.f, 0.f, 0.f); return; }
    int f = i - 12500;

    if (f < 19456) {                       // wtu0: layer1 node W' [608 out][32 k]
        int sec = f >> 9, w = f & 511;
        int col = w >> 5, kq = (w & 31) >> 3, j = w & 7;
        int chunk = sec >> 1, b01 = sec & 1;
        int n = chunk * 32 + b01 * 16 + col;
        int k = kq * 8 + j;
        u16 v = 0;
        if (k < 7) {
            if (n < 300)                  v = f2bf(l0w1[k * 300 + n] - l0w1[(7 + k) * 300 + n]);
            else if (n >= 304 && n < 604) v = f2bf(l0w1[(7 + k) * 300 + (n - 304)]);
        } else if (k == 7) {
            if (n < 300) v = f2bf(l0b1[n]);
        }
        wtu0[f] = v; return;
    }
    f -= 19456;
    if (f < 77824) {                       // wtu1: layer2 node W' [608 out][128 k]
        int sec = f >> 9, w = f & 511;
        int col = w >> 5, kq = (w & 31) >> 3, j = w & 7;
        int chunk = sec >> 3, r = sec & 7, s = r >> 1, b01 = r & 1;
        int n = chunk * 32 + b01 * 16 + col;
        int k = s * 32 + kq * 8 + j;
        u16 v = 0;
        if (k < 100) {
            if (n < 300)                  v = f2bf(l1w1[k * 300 + n] - l1w1[(100 + k) * 300 + n]);
            else if (n >= 304 && n < 604) v = f2bf(l1w1[(100 + k) * 300 + (n - 304)]);
        } else if (k == 100) {
            if (n < 300) v = f2bf(l1b1[n]);
        }
        wtu1[f] = v; return;
    }
    f -= 77824;
    if (f < 204800) {                      // wt2a / wt2b: 300x300, K=320 (KA=10)
        const float* src = (f < 102400) ? l0w2 : l1w2;
        const float* bia = (f < 102400) ? l0b2 : l1b2;
        u16* dst = (f < 102400) ? wt2a : wt2b;
        int f2 = (f < 102400) ? f : f - 102400;
        int sec = f2 >> 9, w = f2 & 511;
        int col = w >> 5, rem = w & 31;
        int n0c = sec / 20, r = sec % 20;
        int s = r >> 1, b01 = r & 1;
        int n = n0c * 32 + b01 * 16 + col, k = s * 32 + rem;
        u16 v = 0;
        if (n < 300) {
            if (k < 300)       v = f2bf(src[k * 300 + n]);
            else if (k == 300) v = f2bf(bia[n]);
        }
        dst[f2] = v;
        return;
    }
    f -= 204800;
    if (f < 71680) {                       // wt3a / wt3b: 300x100 -> [112 n3][320 k]
        const float* src = (f < 35840) ? l0w3 : l1w3;
        const float* bia = (f < 35840) ? l0b3 : l1b3;
        u16* dst = (f < 35840) ? wt3a : wt3b;
        int f2 = (f < 35840) ? f : f - 35840;
        int sec = f2 >> 9, w = f2 & 511;
        int col = w >> 5, rem = w & 31;
        int ch = sec / 7, u = sec % 7;
        int n3 = u * 16 + col, k = ch * 32 + rem;
        u16 v = 0;
        if (n3 < 100) {
            if (k < 300)       v = f2bf(src[k * 100 + n3]);
            else if (k == 300) v = f2bf(bia[n3]);
        }
        dst[f2] = v;
        return;
    }
}

// ---------------------------------------------------------------------------
// Count-sort edges by dst: hist -> exclusive scan -> scatter-fill.
// pos[d] = run END after fill (start = pos[d-1] or 0) -- used by reduce_k.
// ---------------------------------------------------------------------------
__global__ __launch_bounds__(256)
void hist_k(const int* __restrict__ ei, int* __restrict__ hist)
{
    int i = blockIdx.x * 256 + threadIdx.x;
    if (i < E_) atomicAdd(&hist[ei[E_ + i]], 1);
}

__global__ __launch_bounds__(1024)
void scan_k(int* h)   // in-place exclusive scan of h[50000], single block
{
    __shared__ int part[1024];
    const int t = threadIdx.x;
    const int CH = 49;
    int base = t * CH;
    int end = base + CH; if (end > 50000) end = 50000;
    int s = 0;
    for (int i = base; i < end; ++i) s += h[i];
    part[t] = s;
    __syncthreads();
    for (int d = 1; d < 1024; d <<= 1) {
        int v = (t >= d) ? part[t - d] : 0;
        __syncthreads();
        part[t] += v;
        __syncthreads();
    }
    int run = (t ? part[t - 1] : 0);
    for (int i = base; i < end; ++i) { int c = h[i]; h[i] = run; run += c; }
}

__global__ __launch_bounds__(256)
void fill_k(const int* __restrict__ ei, int* __restrict__ pos, int* __restrict__ sei)
{
    int i = blockIdx.x * 256 + threadIdx.x;
    if (i >= E_) return;
    int s = ei[i], d = ei[E_ + i];
    int p = atomicAdd(&pos[d], 1);
    sei[p] = s; sei[E_ + p] = d;
}

// ---------------------------------------------------------------------------
// gemm_uv: per-node GEMM  [U|V][n] = [A_n|1] @ W'  (608 outputs).
// U half (cols 0..303) stored f32 to Ubuf; V half (cols 304..607) stored
// BF16 to Vb (R20: halves the random-gather bytes in edge_uv -- the
// register-file-capped in-flight-load bound R18/R19 isolated).
// KA=1: A=x (bias k=7). KA=4: A=agg0 (bias k=100). Wave = 32 nodes;
// 19 output chunks of 32; LDS transit to row-major.
// ---------------------------------------------------------------------------
template<int KA>
__global__ __launch_bounds__(256, 2)
void gemm_uv(const float* __restrict__ A, const u16* __restrict__ W,
             float* __restrict__ Ubuf, u16* __restrict__ Vb)
{
    __shared__ __align__(16) float SC[4][1024];       // 4KB per wave
    const int tid = threadIdx.x, wave = tid >> 6, lane = tid & 63;
    const int col = lane & 15, kq = lane >> 4;
    const int nb = blockIdx.x * 128 + wave * 32;
    const int fragoff = col * 32 + kq * 8;

    s16x8 aF[2][KA];
    #pragma unroll
    for (int rt = 0; rt < 2; ++rt) {
        int node = nb + rt * 16 + col; if (node >= N_) node = N_ - 1;
        if constexpr (KA == 1) {
            s16x8 t = {0, 0, 0, 0, 0, 0, 0, 0};
            if (kq == 0) {
                const float* r = A + (size_t)node * 7;
                #pragma unroll
                for (int j = 0; j < 7; ++j) t[j] = (short)f2bf(r[j]);
                t[7] = (short)0x3f80;                 // bias slot k=7
            }
            aF[rt][0] = t;
        } else {
            const float* r = A + (size_t)node * 100;
            #pragma unroll
            for (int s = 0; s < KA; ++s) {
                int k0 = s * 32 + kq * 8;
                s16x8 t = {0, 0, 0, 0, 0, 0, 0, 0};
                if (k0 + 8 <= 100) {
                    float4 a = *(const float4*)(r + k0);
                    float4 b = *(const float4*)(r + k0 + 4);
                    t[0] = (short)f2bf(a.x); t[1] = (short)f2bf(a.y);
                    t[2] = (short)f2bf(a.z); t[3] = (short)f2bf(a.w);
                    t[4] = (short)f2bf(b.x); t[5] = (short)f2bf(b.y);
                    t[6] = (short)f2bf(b.z); t[7] = (short)f2bf(b.w);
                } else if (k0 == 96) {
                    float4 a = *(const float4*)(r + 96);
                    t[0] = (short)f2bf(a.x); t[1] = (short)f2bf(a.y);
                    t[2] = (short)f2bf(a.z); t[3] = (short)f2bf(a.w);
                    t[4] = (short)0x3f80;             // bias slot k=100
                }
                aF[rt][s] = t;
            }
        }
    }

    float* SCw = SC[wave];
    #pragma unroll 1
    for (int c = 0; c < 19; ++c) {
        const u16* w0 = W + (size_t)(c * 2 * KA) * 512 + fragoff;
        s16x8 wb[2 * KA];
        #pragma unroll
        for (int t = 0; t < 2 * KA; ++t) wb[t] = ldv(w0 + t * 512);
        f32x4 z = {0.f, 0.f, 0.f, 0.f};
        f32x4 ac[2][2] = {{z, z}, {z, z}};            // [b01][rt]
        #pragma unroll
        for (int s = 0; s < KA; ++s)
            #pragma unroll
            for (int rt = 0; rt < 2; ++rt) {
                ac[0][rt] = MFMA(wb[2 * s],     aF[rt][s], ac[0][rt]);
                ac[1][rt] = MFMA(wb[2 * s + 1], aF[rt][s], ac[1][rt]);
            }
        // transit: ch-major frag -> node-major rows (wave-private, lgkm order)
        #pragma unroll
        for (int cb = 0; cb < 2; ++cb)
            #pragma unroll
            for (int rt = 0; rt < 2; ++rt)
                #pragma unroll
                for (int r = 0; r < 4; ++r)
                    SCw[(rt * 16 + col) * 32 + cb * 16 + kq * 4 + r] = ac[cb][rt][r];
        #pragma unroll
        for (int p = 0; p < 4; ++p) {
            int row = p * 8 + (lane >> 3);
            int node = nb + row;
            if (node < N_) {
                float4 v = *(const float4*)(SCw + row * 32 + (lane & 7) * 4);
                int colb = c * 32 + (lane & 7) * 4;
                if (colb < 304) {                     // U half: f32
                    *(float4*)(Ubuf + (size_t)node * US_ + colb) = v;
                } else {                              // V half: bf16
                    int m = colb - 304;
                    ushort4 pv;
                    pv.x = f2bf(v.x); pv.y = f2bf(v.y);
                    pv.z = f2bf(v.z); pv.w = f2bf(v.w);
                    *(ushort4*)(Vb + (size_t)node * VS_ + m) = pv;
                }
            }
        }
    }
}

// per-chunk GEMM2+GEMM3 compute from named register arrays
#define COMPUTE2(W2R, W3R, CH) {                                              \
    f32x4 z_ = {0.f, 0.f, 0.f, 0.f};                                          \
    f32x4 ac_[2][2] = {{z_, z_}, {z_, z_}};                                   \
    _Pragma("unroll")                                                         \
    for (int s_ = 0; s_ < 10; ++s_) {                                         \
        _Pragma("unroll")                                                     \
        for (int rt_ = 0; rt_ < 2; ++rt_) {                                   \
            ac_[0][rt_] = MFMA(W2R[2 * s_],     a2[rt_][s_], ac_[0][rt_]);    \
            ac_[1][rt_] = MFMA(W2R[2 * s_ + 1], a2[rt_][s_], ac_[1][rt_]);    \
        }                                                                     \
    }                                                                         \
    s16x8 a3_[2];                                                             \
    _Pragma("unroll")                                                         \
    for (int rt_ = 0; rt_ < 2; ++rt_)                                         \
        a3_[rt_] = conv_frag(ac_[0][rt_], ac_[1][rt_], kq, col);              \
    if ((CH) == 9 && kq == 1) {                                               \
        a3_[0][4] = (short)0x3f80;                                            \
        a3_[1][4] = (short)0x3f80;                                            \
    }                                                                         \
    _Pragma("unroll")                                                         \
    for (int u_ = 0; u_ < 7; ++u_) {                                          \
        mac[0][u_] = MFMA(W3R[u_], a3_[0], mac[0][u_]);                       \
        mac[1][u_] = MFMA(W3R[u_], a3_[1], mac[1][u_]);                       \
    }                                                                         \
}

// ---------------------------------------------------------------------------
// edge_uv R20: per-edge H1 = relu(U[dst] + bf16V[src]) -> GEMM2+GEMM3 ->
// msg. R18/R19 A/B proved in-flight-load bytes are register-file capped
// (ILP x TLP product invariant); this round halves the RANDOM-path bytes:
// V loads are one ldv(16B) per chunk instead of two float4 (32B). U stays
// f32 (dst rows sequential under dst-sort -> L2-hot, short latency).
// R16-style per-chunk static weight batches, __launch_bounds__(256,2).
// ---------------------------------------------------------------------------
__global__ __launch_bounds__(256, 2)
void edge_uv(const float* __restrict__ Ubuf, const u16* __restrict__ Vb,
             const int* __restrict__ ei,
             const u16* __restrict__ W2, const u16* __restrict__ W3,
             u16* __restrict__ msg)
{
    __shared__ __align__(16) u16 SCR[4 * 32 * MS_];   // 28,672 B (epilogue)

    const int tid  = threadIdx.x;
    const int wave = tid >> 6, lane = tid & 63;
    const int col  = lane & 15, kq = lane >> 4;
    const int ebase = blockIdx.x * 128 + wave * 32;   // 32 edges per wave
    const int fragoff = col * 32 + kq * 8;            // in-section lane offset

    u16* SCw = SCR + wave * (32 * MS_);

    // ---- build a2 fragments from U[dst] + bf16 V[src] ----
    s16x8 a2[2][10];
    #pragma unroll
    for (int rt = 0; rt < 2; ++rt) {
        const int e = ebase + rt * 16 + col;
        const int dn = ei[E_ + e];                    // x_i (dst)
        const int sn = ei[e];                         // x_j (src)
        const float* Ud = Ubuf + (size_t)dn * US_;
        const u16*  Vsb = Vb  + (size_t)sn * VS_;
        #pragma unroll
        for (int h = 0; h < 2; ++h) {                 // two 5-chunk halves
            float4 ua[5], ub[5];
            s16x8  vv[5];
            #pragma unroll
            for (int q = 0; q < 5; ++q) {
                int k0 = (h * 5 + q) * 32 + kq * 8;
                const float4 zz = make_float4(0.f, 0.f, 0.f, 0.f);
                const s16x8 zv = {0, 0, 0, 0, 0, 0, 0, 0};
                bool ok = (k0 < 304);                 // rows are 304-padded
                ua[q] = ok ? *(const float4*)(Ud + k0)     : zz;
                ub[q] = ok ? *(const float4*)(Ud + k0 + 4) : zz;
                vv[q] = ok ? ldv(Vsb + k0)                 : zv;
            }
            #pragma unroll
            for (int q = 0; q < 5; ++q) {
                unsigned p0 = pkbf(fmaxf(ua[q].x + bf2f((u16)vv[q][0]), 0.f),
                                   fmaxf(ua[q].y + bf2f((u16)vv[q][1]), 0.f));
                unsigned p1 = pkbf(fmaxf(ua[q].z + bf2f((u16)vv[q][2]), 0.f),
                                   fmaxf(ua[q].w + bf2f((u16)vv[q][3]), 0.f));
                unsigned p2 = pkbf(fmaxf(ub[q].x + bf2f((u16)vv[q][4]), 0.f),
                                   fmaxf(ub[q].y + bf2f((u16)vv[q][5]), 0.f));
                unsigned p3 = pkbf(fmaxf(ub[q].z + bf2f((u16)vv[q][6]), 0.f),
                                   fmaxf(ub[q].w + bf2f((u16)vv[q][7]), 0.f));
                union { unsigned u[4]; s16x8 v; } o;
                o.u[0] = p0; o.u[1] = p1; o.u[2] = p2; o.u[3] = p3;
                a2[rt][h * 5 + q] = o.v;
            }
        }
    }
    if (kq == 1) {                                    // GEMM2 k=300 bias slot
        a2[0][9][4] = (short)0x3f80;
        a2[1][9][4] = (short)0x3f80;
    }

    f32x4 mac[2][7];
    #pragma unroll
    for (int rt = 0; rt < 2; ++rt)
        #pragma unroll
        for (int u = 0; u < 7; ++u) { f32x4 z = {0.f, 0.f, 0.f, 0.f}; mac[rt][u] = z; }

    // ---- GEMM2 (K=320) fused with GEMM3, per-chunk static batches ----
    #pragma unroll 1
    for (int ch = 0; ch < 10; ++ch) {
        const u16* w0 = W2 + (size_t)(ch * 20) * 512 + fragoff;
        s16x8 wb[20];                                 // batched chunk loads
        #pragma unroll
        for (int s = 0; s < 20; ++s) wb[s] = ldv(w0 + s * 512);
        f32x4 z = {0.f, 0.f, 0.f, 0.f};
        f32x4 ac[2][2] = {{z, z}, {z, z}};
        #pragma unroll
        for (int s = 0; s < 10; ++s)
            #pragma unroll
            for (int rt = 0; rt < 2; ++rt) {
                ac[0][rt] = MFMA(wb[2 * s],     a2[rt][s], ac[0][rt]);
                ac[1][rt] = MFMA(wb[2 * s + 1], a2[rt][s], ac[1][rt]);
            }
        // issue W3 loads before conv_frag (overlap bpermute latency)
        s16x8 w3b[7];
        #pragma unroll
        for (int u = 0; u < 7; ++u)
            w3b[u] = ldv(W3 + (size_t)(ch * 7 + u) * 512 + fragoff);
        s16x8 a3[2];
        #pragma unroll
        for (int rt = 0; rt < 2; ++rt)
            a3[rt] = conv_frag(ac[0][rt], ac[1][rt], kq, col);
        if (ch == 9 && kq == 1) {                     // GEMM3 k=300 bias slot
            a3[0][4] = (short)0x3f80;
            a3[1][4] = (short)0x3f80;
        }
        #pragma unroll
        for (int u = 0; u < 7; ++u) {
            mac[0][u] = MFMA(w3b[u], a3[0], mac[0][u]);
            mac[1][u] = MFMA(w3b[u], a3[1], mac[1][u]);
        }
    }

    // ---- epilogue: mac rows=out-channels, cols=edges. Pack relu'd pairs to
    //      LDS [32 edges][112 ch], then coalesced 16B-lane global stores ----
    #pragma unroll
    for (int rt = 0; rt < 2; ++rt) {
        const int row = rt * 16 + col;
        #pragma unroll
        for (int u = 0; u < 7; ++u) {
            unsigned p0 = pkbf(fmaxf(mac[rt][u][0], 0.f), fmaxf(mac[rt][u][1], 0.f));
            unsigned p1 = pkbf(fmaxf(mac[rt][u][2], 0.f), fmaxf(mac[rt][u][3], 0.f));
            int chb = u * 16 + kq * 4;
            *(unsigned*)(SCw + row * MS_ + chb)     = p0;
            *(unsigned*)(SCw + row * MS_ + chb + 2) = p1;
        }
    }
    // wave-private region: lgkmcnt ordering only
    u16* gdst = msg + (size_t)ebase * MS_;
    #pragma unroll
    for (int q2 = 0; q2 < 7; ++q2) {
        s16x8 v = ldv(SCw + q2 * 512 + lane * 8);
        *(s16x8*)(gdst + q2 * 512 + lane * 8) = v;
    }
}

// ---------------------------------------------------------------------------
// reduce_k: segment-max over sorted msg runs (stride MS_). One wave per node.
// Writes EVERY node (empty run -> 0), so agg needs no zero-init.
// ---------------------------------------------------------------------------
__global__ __launch_bounds__(256)
void reduce_k(const u16* __restrict__ msg, const int* __restrict__ pos,
              float* __restrict__ agg)
{
    const int n = blockIdx.x * 4 + (threadIdx.x >> 6);
    if (n >= N_) return;
    const int lane = threadIdx.x & 63;
    const int start = n ? pos[n - 1] : 0;
    const int end   = pos[n];
    float m0 = 0.f, m1 = 0.f;
    for (int e = start; e < end; ++e) {
        const u16* row = msg + (size_t)e * MS_;
        m0 = fmaxf(m0, bf2f(row[lane]));
        if (lane < 36) m1 = fmaxf(m1, bf2f(row[64 + lane]));
    }
    agg[(size_t)n * 100 + lane] = m0;
    if (lane < 36) agg[(size_t)n * 100 + 64 + lane] = m1;
}

// ---------------------------------------------------------------------------
// pool: one block per graph (batch sorted -> binary-search bounds).
// ---------------------------------------------------------------------------
__global__ __launch_bounds__(256)
void pool(const float* __restrict__ agg1, const int* __restrict__ batch,
          const float* __restrict__ u, float* __restrict__ pooled)
{
    const int g = blockIdx.x;
    int lo = 0, hi = N_;
    while (lo < hi) { int mid = (lo + hi) >> 1; if (batch[mid] < g) lo = mid + 1; else hi = mid; }
    const int start = lo;
    int lo2 = start, hi2 = N_;
    while (lo2 < hi2) { int mid = (lo2 + hi2) >> 1; if (batch[mid] < g + 1) lo2 = mid + 1; else hi2 = mid; }
    const int end = lo2;

    const int c = threadIdx.x & 127, half = threadIdx.x >> 7;
    float sm = 0.f, mx = 0.f;
    if (c < 100)
        for (int n = start + half; n < end; n += 2) {
            float v = agg1[(size_t)n * 100 + c];
            sm += v; mx = fmaxf(mx, v);
        }
    __shared__ float ssum[128], smax[128];
    if (half) { ssum[c] = sm; smax[c] = mx; }
    __syncthreads();
    if (!half && c < 100) {
        sm += ssum[c]; mx = fmaxf(mx, smax[c]);
        int cnt = end - start;
        pooled[g * 302 + c]       = sm;
        pooled[g * 302 + 100 + c] = sm / fmaxf((float)cnt, 1.f);
        pooled[g * 302 + 200 + c] = mx;
    }
    if (threadIdx.x == 0) {
        pooled[g * 302 + 300] = u[g * 2];
        pooled[g * 302 + 301] = u[g * 2 + 1];
    }
}

// ---------------------------------------------------------------------------
// final 302 -> 100 -> 100 -> 2 MLP, one block per graph, fp32
// ---------------------------------------------------------------------------
__global__ __launch_bounds__(128)
void final_mlp(const float* __restrict__ pooled,
               const float* __restrict__ w1, const float* __restrict__ b1,
               const float* __restrict__ w2, const float* __restrict__ b2,
               const float* __restrict__ w3, const float* __restrict__ b3,
               float* __restrict__ out)
{
    const int g = blockIdx.x, t = threadIdx.x;
    __shared__ float P[302], T1[100], T2[100];
    for (int i = t; i < 302; i += 128) P[i] = pooled[g * 302 + i];
    __syncthreads();
    if (t < 100) {
        float a = b1[t];
        for (int i = 0; i < 302; ++i) a = fmaf(P[i], w1[i * 100 + t], a);
        T1[t] = fmaxf(a, 0.f);
    }
    __syncthreads();
    if (t < 100) {
        float a = b2[t];
        for (int i = 0; i < 100; ++i) a = fmaf(T1[i], w2[i * 100 + t], a);
        T2[t] = fmaxf(a, 0.f);
    }
    __syncthreads();
    if (t < 2) {
        float a = b3[t];
        for (int i = 0; i < 100; ++i) a = fmaf(T2[i], w3[i * 2 + t], a);
        out[g * 2 + t] = a;
    }
}

// ---------------------------------------------------------------------------
extern "C" void kernel_launch(void* const* d_in, const int* in_sizes, int n_in,
                              void* d_out, int out_size, void* d_ws, size_t ws_size,
                              hipStream_t stream)
{
    const float* x     = (const float*)d_in[0];
    const int*   ei    = (const int*)d_in[1];
    const int*   batch = (const int*)d_in[2];
    const float* uu    = (const float*)d_in[3];
    const float *l0w1 = (const float*)d_in[4],  *l0b1 = (const float*)d_in[5];
    const float *l0w2 = (const float*)d_in[6],  *l0b2 = (const float*)d_in[7];
    const float *l0w3 = (const float*)d_in[8],  *l0b3 = (const float*)d_in[9];
    const float *l1w1 = (const float*)d_in[10], *l1b1 = (const float*)d_in[11];
    const float *l1w2 = (const float*)d_in[12], *l1b2 = (const float*)d_in[13];
    const float *l1w3 = (const float*)d_in[14], *l1b3 = (const float*)d_in[15];
    const float *lw1  = (const float*)d_in[16], *lb1  = (const float*)d_in[17];
    const float *lw2  = (const float*)d_in[18], *lb2  = (const float*)d_in[19];
    const float *lw3  = (const float*)d_in[20], *lb3  = (const float*)d_in[21];

    char* w = (char*)d_ws;
    float* agg0   = (float*)(w);                    //  20,000,000 B
    float* agg1   = (float*)(w + 20000000);         //  20,000,000 B
    float* pooled = (float*)(w + 40000000);         //      77,312 B
    u16* wtu0 = (u16*)(w + 40077312);               //      38,912 B
    u16* wtu1 = (u16*)(w + 40116224);               //     155,648 B
    u16* wt2a = (u16*)(w + 40271872);               //     204,800 B
    u16* wt2b = (u16*)(w + 40476672);               //     204,800 B
    u16* wt3a = (u16*)(w + 40681472);               //      71,680 B
    u16* wt3b = (u16*)(w + 40753152);               //      71,680 B
    int* hist = (int*)(w + 40824832);               //     200,000 B (run ends)
    int* sei  = (int*)(w + 41024832);               //   3,200,000 B (sorted)
    u16* msg  = (u16*)(w + 44224832);               //  89,600,000 B (224B rows)
    float* Ubuf = (float*)(w + 133824832);          //  60,800,000 B (N x 304 f32)
    u16*   Vb   = (u16*)(w + 194624832);            //  30,400,000 B (N x 304 bf16)
                                                    // total ~214.6 MiB (+slack)

    ModelGNN_35304631174019_kernel<<<1509, 256, 0, stream>>>(
        l0w1, l0w2, l0w3, l1w1, l1w2, l1w3,
        l0b1, l0b2, l0b3, l1b1, l1b2, l1b3,
        (float4*)hist, wtu0, wtu1, wt2a, wt2b, wt3a, wt3b);
    hist_k<<<1563, 256, 0, stream>>>(ei, hist);
    scan_k<<<1, 1024, 0, stream>>>(hist);
    fill_k<<<1563, 256, 0, stream>>>(ei, hist, sei);
    gemm_uv<1><<<391, 256, 0, stream>>>(x, wtu0, Ubuf, Vb);
    edge_uv<<<3125, 256, 0, stream>>>(Ubuf, Vb, sei, wt2a, wt3a, msg);
    reduce_k<<<12500, 256, 0, stream>>>(msg, hist, agg0);
    gemm_uv<4><<<391, 256, 0, stream>>>(agg0, wtu1, Ubuf, Vb);
    edge_uv<<<3125, 256, 0, stream>>>(Ubuf, Vb, sei, wt2b, wt3b, msg);
    reduce_k<<<12500, 256, 0, stream>>>(msg, hist, agg1);
    pool<<<G_, 256, 0, stream>>>(agg1, batch, uu, pooled);
    final_mlp<<<G_, 128, 0, stream>>>(pooled, lw1, lb1, lw2, lb2, lw3, lb3, (float*)d_out);
}

// Round 21
// 1070.251 us; speedup vs baseline: 1.1406x; 1.0099x over previous
//
#include <hip/hip_runtime.h>

typedef unsigned short u16;
typedef short s16x8 __attribute__((ext_vector_type(8)));   // 8 bf16 bit-patterns
typedef float f32x4 __attribute__((ext_vector_type(4)));

#define DI __device__ __forceinline__

constexpr int N_ = 50000;
constexpr int E_ = 400000;
constexpr int G_ = 64;
constexpr int MS_ = 112;            // msg row stride in u16 (224 B)
constexpr int UVS_ = 608;           // UV row stride in u16 bf16: [U 0..303 | V 304..607]

DI u16 f2bf(float f) {
    union { unsigned u; float f; } c; c.f = f;
    unsigned u = c.u;
    u += 0x7fffu + ((u >> 16) & 1u);   // RNE
    return (u16)(u >> 16);
}
DI float bf2f(u16 v) {
    union { unsigned u; float f; } c; c.u = (unsigned)v << 16;
    return c.f;
}
DI unsigned pkbf(float lo, float hi) {   // u32 = bf16(lo) | bf16(hi)<<16 (RNE)
    return (unsigned)f2bf(lo) | ((unsigned)f2bf(hi) << 16);
}

DI s16x8 ldv(const u16* p) { return *(const s16x8*)p; }
DI f32x4 MFMA(s16x8 a, s16x8 b, f32x4 c) {
    return __builtin_amdgcn_mfma_f32_16x16x32_bf16(a, b, c, 0, 0, 0);
}

// ---------------------------------------------------------------------------
// C-frag pair (transposed GEMM output: rows=channels, cols=edges) -> next
// GEMM's B-frag (lane&15=edge, k=kq*8+j), fused ReLU. 8 pkbf + 8
// ds_bpermute + 4 selects, no LDS storage. Verified vs C/D layout
// col=lane&15,row=kq*4+r (m89).
// ---------------------------------------------------------------------------
DI s16x8 conv_frag(const f32x4 a0, const f32x4 a1, int kq, int col) {
    unsigned c0 = pkbf(fmaxf(a0[0], 0.f), fmaxf(a0[1], 0.f));
    unsigned c1 = pkbf(fmaxf(a0[2], 0.f), fmaxf(a0[3], 0.f));
    unsigned c2 = pkbf(fmaxf(a1[0], 0.f), fmaxf(a1[1], 0.f));
    unsigned c3 = pkbf(fmaxf(a1[2], 0.f), fmaxf(a1[3], 0.f));
    int aA = (kq & 1) * 128 + col * 4;       // src lane (kq&1)*32 + col
    int aB = aA + 64;                        // src lane (kq&1)*32 + 16 + col
    unsigned A0 = __builtin_amdgcn_ds_bpermute(aA, (int)c0);
    unsigned A1 = __builtin_amdgcn_ds_bpermute(aA, (int)c1);
    unsigned A2 = __builtin_amdgcn_ds_bpermute(aA, (int)c2);
    unsigned A3 = __builtin_amdgcn_ds_bpermute(aA, (int)c3);
    unsigned B0 = __builtin_amdgcn_ds_bpermute(aB, (int)c0);
    unsigned B1 = __builtin_amdgcn_ds_bpermute(aB, (int)c1);
    unsigned B2 = __builtin_amdgcn_ds_bpermute(aB, (int)c2);
    unsigned B3 = __builtin_amdgcn_ds_bpermute(aB, (int)c3);
    bool hi = (kq >> 1) != 0;
    union { unsigned u[4]; s16x8 v; } o;
    o.u[0] = hi ? A2 : A0;
    o.u[1] = hi ? A3 : A1;
    o.u[2] = hi ? B2 : B0;
    o.u[3] = hi ? B3 : B1;
    return o.v;
}

// ---------------------------------------------------------------------------
// Named kernel: zero hist + repack weights f32 -> bf16 in MFMA-FRAGMENT-
// ORDER sections (elem (col,kq,j) at col*32+kq*8+j).
// GEMM1 hoisted to node level: H1 = relu([xi|xj-xi]@W1+b) =
// relu(U[dst]+V[src]) with U = A@(Wa-Wb)+b, V = A@Wb per NODE. wtu* hold
// W' = [Wa-Wb | 0pad | Wb | 0pad] (608 outputs) with bias in k-pad row
// (U half only). wt2/wt3 unchanged (bias in k=300 row).
// ---------------------------------------------------------------------------
__global__ __launch_bounds__(256)
void ModelGNN_35304631174019_kernel(
          const float* __restrict__ l0w1, const float* __restrict__ l0w2,
          const float* __restrict__ l0w3, const float* __restrict__ l1w1,
          const float* __restrict__ l1w2, const float* __restrict__ l1w3,
          const float* __restrict__ l0b1, const float* __restrict__ l0b2,
          const float* __restrict__ l0b3, const float* __restrict__ l1b1,
          const float* __restrict__ l1b2, const float* __restrict__ l1b3,
          float4* __restrict__ histz,
          u16* __restrict__ wtu0, u16* __restrict__ wtu1,
          u16* __restrict__ wt2a, u16* __restrict__ wt2b,
          u16* __restrict__ wt3a, u16* __restrict__ wt3b)
{
    int i = blockIdx.x * 256 + threadIdx.x;
    if (i < 12500) { histz[i] = make_float4(0.f, 0.f, 0.f, 0.f); return; }
    int f = i - 12500;

    if (f < 19456) {                       // wtu0: layer1 node W' [608 out][32 k]
        int sec = f >> 9, w = f & 511;
        int col = w >> 5, kq = (w & 31) >> 3, j = w & 7;
        int chunk = sec >> 1, b01 = sec & 1;
        int n = chunk * 32 + b01 * 16 + col;
        int k = kq * 8 + j;
        u16 v = 0;
        if (k < 7) {
            if (n < 300)                  v = f2bf(l0w1[k * 300 + n] - l0w1[(7 + k) * 300 + n]);
            else if (n >= 304 && n < 604) v = f2bf(l0w1[(7 + k) * 300 + (n - 304)]);
        } else if (k == 7) {
            if (n < 300) v = f2bf(l0b1[n]);
        }
        wtu0[f] = v; return;
    }
    f -= 19456;
    if (f < 77824) {                       // wtu1: layer2 node W' [608 out][128 k]
        int sec = f >> 9, w = f & 511;
        int col = w >> 5, kq = (w & 31) >> 3, j = w & 7;
        int chunk = sec >> 3, r = sec & 7, s = r >> 1, b01 = r & 1;
        int n = chunk * 32 + b01 * 16 + col;
        int k = s * 32 + kq * 8 + j;
        u16 v = 0;
        if (k < 100) {
            if (n < 300)                  v = f2bf(l1w1[k * 300 + n] - l1w1[(100 + k) * 300 + n]);
            else if (n >= 304 && n < 604) v = f2bf(l1w1[(100 + k) * 300 + (n - 304)]);
        } else if (k == 100) {
            if (n < 300) v = f2bf(l1b1[n]);
        }
        wtu1[f] = v; return;
    }
    f -= 77824;
    if (f < 204800) {                      // wt2a / wt2b: 300x300, K=320 (KA=10)
        const float* src = (f < 102400) ? l0w2 : l1w2;
        const float* bia = (f < 102400) ? l0b2 : l1b2;
        u16* dst = (f < 102400) ? wt2a : wt2b;
        int f2 = (f < 102400) ? f : f - 102400;
        int sec = f2 >> 9, w = f2 & 511;
        int col = w >> 5, rem = w & 31;
        int n0c = sec / 20, r = sec % 20;
        int s = r >> 1, b01 = r & 1;
        int n = n0c * 32 + b01 * 16 + col, k = s * 32 + rem;
        u16 v = 0;
        if (n < 300) {
            if (k < 300)       v = f2bf(src[k * 300 + n]);
            else if (k == 300) v = f2bf(bia[n]);
        }
        dst[f2] = v;
        return;
    }
    f -= 204800;
    if (f < 71680) {                       // wt3a / wt3b: 300x100 -> [112 n3][320 k]
        const float* src = (f < 35840) ? l0w3 : l1w3;
        const float* bia = (f < 35840) ? l0b3 : l1b3;
        u16* dst = (f < 35840) ? wt3a : wt3b;
        int f2 = (f < 35840) ? f : f - 35840;
        int sec = f2 >> 9, w = f2 & 511;
        int col = w >> 5, rem = w & 31;
        int ch = sec / 7, u = sec % 7;
        int n3 = u * 16 + col, k = ch * 32 + rem;
        u16 v = 0;
        if (n3 < 100) {
            if (k < 300)       v = f2bf(src[k * 100 + n3]);
            else if (k == 300) v = f2bf(bia[n3]);
        }
        dst[f2] = v;
        return;
    }
}

// ---------------------------------------------------------------------------
// Count-sort edges by dst: hist -> exclusive scan -> scatter-fill.
// pos[d] = run END after fill (start = pos[d-1] or 0) -- used by reduce_k.
// ---------------------------------------------------------------------------
__global__ __launch_bounds__(256)
void hist_k(const int* __restrict__ ei, int* __restrict__ hist)
{
    int i = blockIdx.x * 256 + threadIdx.x;
    if (i < E_) atomicAdd(&hist[ei[E_ + i]], 1);
}

__global__ __launch_bounds__(1024)
void scan_k(int* h)   // in-place exclusive scan of h[50000], single block
{
    __shared__ int part[1024];
    const int t = threadIdx.x;
    const int CH = 49;
    int base = t * CH;
    int end = base + CH; if (end > 50000) end = 50000;
    int s = 0;
    for (int i = base; i < end; ++i) s += h[i];
    part[t] = s;
    __syncthreads();
    for (int d = 1; d < 1024; d <<= 1) {
        int v = (t >= d) ? part[t - d] : 0;
        __syncthreads();
        part[t] += v;
        __syncthreads();
    }
    int run = (t ? part[t - 1] : 0);
    for (int i = base; i < end; ++i) { int c = h[i]; h[i] = run; run += c; }
}

__global__ __launch_bounds__(256)
void fill_k(const int* __restrict__ ei, int* __restrict__ pos, int* __restrict__ sei)
{
    int i = blockIdx.x * 256 + threadIdx.x;
    if (i >= E_) return;
    int s = ei[i], d = ei[E_ + i];
    int p = atomicAdd(&pos[d], 1);
    sei[p] = s; sei[E_ + p] = d;
}

// ---------------------------------------------------------------------------
// gemm_uv: per-node GEMM  [U|V][n] = [A_n|1] @ W'  (608 outputs), ALL BF16
// out (R21: U bf16 too -> whole row-tile batches in edge_uv fit 80 regs,
// one latency exposure per rt; U stream bytes halve; writes 91->61 MB).
// KA=1: A=x (bias k=7). KA=4: A=agg0 (bias k=100). Wave = 32 nodes;
// 19 output chunks of 32; LDS transit to row-major.
// ---------------------------------------------------------------------------
template<int KA>
__global__ __launch_bounds__(256, 2)
void gemm_uv(const float* __restrict__ A, const u16* __restrict__ W,
             u16* __restrict__ UVb)
{
    __shared__ __align__(16) float SC[4][1024];       // 4KB per wave
    const int tid = threadIdx.x, wave = tid >> 6, lane = tid & 63;
    const int col = lane & 15, kq = lane >> 4;
    const int nb = blockIdx.x * 128 + wave * 32;
    const int fragoff = col * 32 + kq * 8;

    s16x8 aF[2][KA];
    #pragma unroll
    for (int rt = 0; rt < 2; ++rt) {
        int node = nb + rt * 16 + col; if (node >= N_) node = N_ - 1;
        if constexpr (KA == 1) {
            s16x8 t = {0, 0, 0, 0, 0, 0, 0, 0};
            if (kq == 0) {
                const float* r = A + (size_t)node * 7;
                #pragma unroll
                for (int j = 0; j < 7; ++j) t[j] = (short)f2bf(r[j]);
                t[7] = (short)0x3f80;                 // bias slot k=7
            }
            aF[rt][0] = t;
        } else {
            const float* r = A + (size_t)node * 100;
            #pragma unroll
            for (int s = 0; s < KA; ++s) {
                int k0 = s * 32 + kq * 8;
                s16x8 t = {0, 0, 0, 0, 0, 0, 0, 0};
                if (k0 + 8 <= 100) {
                    float4 a = *(const float4*)(r + k0);
                    float4 b = *(const float4*)(r + k0 + 4);
                    t[0] = (short)f2bf(a.x); t[1] = (short)f2bf(a.y);
                    t[2] = (short)f2bf(a.z); t[3] = (short)f2bf(a.w);
                    t[4] = (short)f2bf(b.x); t[5] = (short)f2bf(b.y);
                    t[6] = (short)f2bf(b.z); t[7] = (short)f2bf(b.w);
                } else if (k0 == 96) {
                    float4 a = *(const float4*)(r + 96);
                    t[0] = (short)f2bf(a.x); t[1] = (short)f2bf(a.y);
                    t[2] = (short)f2bf(a.z); t[3] = (short)f2bf(a.w);
                    t[4] = (short)0x3f80;             // bias slot k=100
                }
                aF[rt][s] = t;
            }
        }
    }

    float* SCw = SC[wave];
    #pragma unroll 1
    for (int c = 0; c < 19; ++c) {
        const u16* w0 = W + (size_t)(c * 2 * KA) * 512 + fragoff;
        s16x8 wb[2 * KA];
        #pragma unroll
        for (int t = 0; t < 2 * KA; ++t) wb[t] = ldv(w0 + t * 512);
        f32x4 z = {0.f, 0.f, 0.f, 0.f};
        f32x4 ac[2][2] = {{z, z}, {z, z}};            // [b01][rt]
        #pragma unroll
        for (int s = 0; s < KA; ++s)
            #pragma unroll
            for (int rt = 0; rt < 2; ++rt) {
                ac[0][rt] = MFMA(wb[2 * s],     aF[rt][s], ac[0][rt]);
                ac[1][rt] = MFMA(wb[2 * s + 1], aF[rt][s], ac[1][rt]);
            }
        // transit: ch-major frag -> node-major rows (wave-private, lgkm order)
        #pragma unroll
        for (int cb = 0; cb < 2; ++cb)
            #pragma unroll
            for (int rt = 0; rt < 2; ++rt)
                #pragma unroll
                for (int r = 0; r < 4; ++r)
                    SCw[(rt * 16 + col) * 32 + cb * 16 + kq * 4 + r] = ac[cb][rt][r];
        #pragma unroll
        for (int p = 0; p < 4; ++p) {
            int row = p * 8 + (lane >> 3);
            int node = nb + row;
            if (node < N_) {
                float4 v = *(const float4*)(SCw + row * 32 + (lane & 7) * 4);
                int colb = c * 32 + (lane & 7) * 4;
                ushort4 pv;
                pv.x = f2bf(v.x); pv.y = f2bf(v.y);
                pv.z = f2bf(v.z); pv.w = f2bf(v.w);
                *(ushort4*)(UVb + (size_t)node * UVS_ + colb) = pv;
            }
        }
    }
}

// per-chunk GEMM2+GEMM3 compute from named register arrays
#define COMPUTE2(W2R, W3R, CH) {                                              \
    f32x4 z_ = {0.f, 0.f, 0.f, 0.f};                                          \
    f32x4 ac_[2][2] = {{z_, z_}, {z_, z_}};                                   \
    _Pragma("unroll")                                                         \
    for (int s_ = 0; s_ < 10; ++s_) {                                         \
        _Pragma("unroll")                                                     \
        for (int rt_ = 0; rt_ < 2; ++rt_) {                                   \
            ac_[0][rt_] = MFMA(W2R[2 * s_],     a2[rt_][s_], ac_[0][rt_]);    \
            ac_[1][rt_] = MFMA(W2R[2 * s_ + 1], a2[rt_][s_], ac_[1][rt_]);    \
        }                                                                     \
    }                                                                         \
    s16x8 a3_[2];                                                             \
    _Pragma("unroll")                                                         \
    for (int rt_ = 0; rt_ < 2; ++rt_)                                         \
        a3_[rt_] = conv_frag(ac_[0][rt_], ac_[1][rt_], kq, col);              \
    if ((CH) == 9 && kq == 1) {                                               \
        a3_[0][4] = (short)0x3f80;                                            \
        a3_[1][4] = (short)0x3f80;                                            \
    }                                                                         \
    _Pragma("unroll")                                                         \
    for (int u_ = 0; u_ < 7; ++u_) {                                          \
        mac[0][u_] = MFMA(W3R[u_], a3_[0], mac[0][u_]);                       \
        mac[1][u_] = MFMA(W3R[u_], a3_[1], mac[1][u_]);                       \
    }                                                                         \
}

// ---------------------------------------------------------------------------
// edge_uv R21: per-edge H1 = relu(bf16 U[dst] + bf16 V[src]) -> GEMM2+GEMM3
// -> msg. The R18-R20 arc proved this kernel is bound by random-gather
// bytes held in flight per register (ILPxTLP invariance; R20 byte-halving
// -> -17%). R21 finishes it: U bf16 too -> a full row-tile's 20 loads
// (10 U + 10 V, 80 regs) batch in ONE latency exposure per rt.
// R16-style per-chunk static weight batches, __launch_bounds__(256,2).
// ---------------------------------------------------------------------------
__global__ __launch_bounds__(256, 2)
void edge_uv(const u16* __restrict__ UVb, const int* __restrict__ ei,
             const u16* __restrict__ W2, const u16* __restrict__ W3,
             u16* __restrict__ msg)
{
    __shared__ __align__(16) u16 SCR[4 * 32 * MS_];   // 28,672 B (epilogue)

    const int tid  = threadIdx.x;
    const int wave = tid >> 6, lane = tid & 63;
    const int col  = lane & 15, kq = lane >> 4;
    const int ebase = blockIdx.x * 128 + wave * 32;   // 32 edges per wave
    const int fragoff = col * 32 + kq * 8;            // in-section lane offset

    u16* SCw = SCR + wave * (32 * MS_);

    // ---- build a2 fragments from bf16 U[dst] + bf16 V[src] ----
    s16x8 a2[2][10];
    #pragma unroll
    for (int rt = 0; rt < 2; ++rt) {
        const int e = ebase + rt * 16 + col;
        const int dn = ei[E_ + e];                    // x_i (dst)
        const int sn = ei[e];                         // x_j (src)
        const u16* Ur = UVb + (size_t)dn * UVS_;
        const u16* Vr = UVb + (size_t)sn * UVS_ + 304;
        s16x8 uu[10], vv[10];
        #pragma unroll
        for (int q = 0; q < 10; ++q) {                // ONE batch per rt
            int k0 = q * 32 + kq * 8;
            const s16x8 zv = {0, 0, 0, 0, 0, 0, 0, 0};
            bool ok = (k0 < 304);                     // rows are 304-padded
            uu[q] = ok ? ldv(Ur + k0) : zv;
            vv[q] = ok ? ldv(Vr + k0) : zv;
        }
        #pragma unroll
        for (int q = 0; q < 10; ++q) {
            unsigned p0 = pkbf(
                fmaxf(bf2f((u16)uu[q][0]) + bf2f((u16)vv[q][0]), 0.f),
                fmaxf(bf2f((u16)uu[q][1]) + bf2f((u16)vv[q][1]), 0.f));
            unsigned p1 = pkbf(
                fmaxf(bf2f((u16)uu[q][2]) + bf2f((u16)vv[q][2]), 0.f),
                fmaxf(bf2f((u16)uu[q][3]) + bf2f((u16)vv[q][3]), 0.f));
            unsigned p2 = pkbf(
                fmaxf(bf2f((u16)uu[q][4]) + bf2f((u16)vv[q][4]), 0.f),
                fmaxf(bf2f((u16)uu[q][5]) + bf2f((u16)vv[q][5]), 0.f));
            unsigned p3 = pkbf(
                fmaxf(bf2f((u16)uu[q][6]) + bf2f((u16)vv[q][6]), 0.f),
                fmaxf(bf2f((u16)uu[q][7]) + bf2f((u16)vv[q][7]), 0.f));
            union { unsigned u[4]; s16x8 v; } o;
            o.u[0] = p0; o.u[1] = p1; o.u[2] = p2; o.u[3] = p3;
            a2[rt][q] = o.v;
        }
    }
    if (kq == 1) {                                    // GEMM2 k=300 bias slot
        a2[0][9][4] = (short)0x3f80;
        a2[1][9][4] = (short)0x3f80;
    }

    f32x4 mac[2][7];
    #pragma unroll
    for (int rt = 0; rt < 2; ++rt)
        #pragma unroll
        for (int u = 0; u < 7; ++u) { f32x4 z = {0.f, 0.f, 0.f, 0.f}; mac[rt][u] = z; }

    // ---- GEMM2 (K=320) fused with GEMM3, per-chunk static batches ----
    #pragma unroll 1
    for (int ch = 0; ch < 10; ++ch) {
        const u16* w0 = W2 + (size_t)(ch * 20) * 512 + fragoff;
        s16x8 wb[20];                                 // batched chunk loads
        #pragma unroll
        for (int s = 0; s < 20; ++s) wb[s] = ldv(w0 + s * 512);
        f32x4 z = {0.f, 0.f, 0.f, 0.f};
        f32x4 ac[2][2] = {{z, z}, {z, z}};
        #pragma unroll
        for (int s = 0; s < 10; ++s)
            #pragma unroll
            for (int rt = 0; rt < 2; ++rt) {
                ac[0][rt] = MFMA(wb[2 * s],     a2[rt][s], ac[0][rt]);
                ac[1][rt] = MFMA(wb[2 * s + 1], a2[rt][s], ac[1][rt]);
            }
        // issue W3 loads before conv_frag (overlap bpermute latency)
        s16x8 w3b[7];
        #pragma unroll
        for (int u = 0; u < 7; ++u)
            w3b[u] = ldv(W3 + (size_t)(ch * 7 + u) * 512 + fragoff);
        s16x8 a3[2];
        #pragma unroll
        for (int rt = 0; rt < 2; ++rt)
            a3[rt] = conv_frag(ac[0][rt], ac[1][rt], kq, col);
        if (ch == 9 && kq == 1) {                     // GEMM3 k=300 bias slot
            a3[0][4] = (short)0x3f80;
            a3[1][4] = (short)0x3f80;
        }
        #pragma unroll
        for (int u = 0; u < 7; ++u) {
            mac[0][u] = MFMA(w3b[u], a3[0], mac[0][u]);
            mac[1][u] = MFMA(w3b[u], a3[1], mac[1][u]);
        }
    }

    // ---- epilogue: mac rows=out-channels, cols=edges. Pack relu'd pairs to
    //      LDS [32 edges][112 ch], then coalesced 16B-lane global stores ----
    #pragma unroll
    for (int rt = 0; rt < 2; ++rt) {
        const int row = rt * 16 + col;
        #pragma unroll
        for (int u = 0; u < 7; ++u) {
            unsigned p0 = pkbf(fmaxf(mac[rt][u][0], 0.f), fmaxf(mac[rt][u][1], 0.f));
            unsigned p1 = pkbf(fmaxf(mac[rt][u][2], 0.f), fmaxf(mac[rt][u][3], 0.f));
            int chb = u * 16 + kq * 4;
            *(unsigned*)(SCw + row * MS_ + chb)     = p0;
            *(unsigned*)(SCw + row * MS_ + chb + 2) = p1;
        }
    }
    // wave-private region: lgkmcnt ordering only
    u16* gdst = msg + (size_t)ebase * MS_;
    #pragma unroll
    for (int q2 = 0; q2 < 7; ++q2) {
        s16x8 v = ldv(SCw + q2 * 512 + lane * 8);
        *(s16x8*)(gdst + q2 * 512 + lane * 8) = v;
    }
}

// ---------------------------------------------------------------------------
// reduce_k: segment-max over sorted msg runs (stride MS_). One wave per node.
// Writes EVERY node (empty run -> 0), so agg needs no zero-init.
// ---------------------------------------------------------------------------
__global__ __launch_bounds__(256)
void reduce_k(const u16* __restrict__ msg, const int* __restrict__ pos,
              float* __restrict__ agg)
{
    const int n = blockIdx.x * 4 + (threadIdx.x >> 6);
    if (n >= N_) return;
    const int lane = threadIdx.x & 63;
    const int start = n ? pos[n - 1] : 0;
    const int end   = pos[n];
    float m0 = 0.f, m1 = 0.f;
    for (int e = start; e < end; ++e) {
        const u16* row = msg + (size_t)e * MS_;
        m0 = fmaxf(m0, bf2f(row[lane]));
        if (lane < 36) m1 = fmaxf(m1, bf2f(row[64 + lane]));
    }
    agg[(size_t)n * 100 + lane] = m0;
    if (lane < 36) agg[(size_t)n * 100 + 64 + lane] = m1;
}

// ---------------------------------------------------------------------------
// pool: one block per graph (batch sorted -> binary-search bounds).
// ---------------------------------------------------------------------------
__global__ __launch_bounds__(256)
void pool(const float* __restrict__ agg1, const int* __restrict__ batch,
          const float* __restrict__ u, float* __restrict__ pooled)
{
    const int g = blockIdx.x;
    int lo = 0, hi = N_;
    while (lo < hi) { int mid = (lo + hi) >> 1; if (batch[mid] < g) lo = mid + 1; else hi = mid; }
    const int start = lo;
    int lo2 = start, hi2 = N_;
    while (lo2 < hi2) { int mid = (lo2 + hi2) >> 1; if (batch[mid] < g + 1) lo2 = mid + 1; else hi2 = mid; }
    const int end = lo2;

    const int c = threadIdx.x & 127, half = threadIdx.x >> 7;
    float sm = 0.f, mx = 0.f;
    if (c < 100)
        for (int n = start + half; n < end; n += 2) {
            float v = agg1[(size_t)n * 100 + c];
            sm += v; mx = fmaxf(mx, v);
        }
    __shared__ float ssum[128], smax[128];
    if (half) { ssum[c] = sm; smax[c] = mx; }
    __syncthreads();
    if (!half && c < 100) {
        sm += ssum[c]; mx = fmaxf(mx, smax[c]);
        int cnt = end - start;
        pooled[g * 302 + c]       = sm;
        pooled[g * 302 + 100 + c] = sm / fmaxf((float)cnt, 1.f);
        pooled[g * 302 + 200 + c] = mx;
    }
    if (threadIdx.x == 0) {
        pooled[g * 302 + 300] = u[g * 2];
        pooled[g * 302 + 301] = u[g * 2 + 1];
    }
}

// ---------------------------------------------------------------------------
// final 302 -> 100 -> 100 -> 2 MLP, one block per graph, fp32
// ---------------------------------------------------------------------------
__global__ __launch_bounds__(128)
void final_mlp(const float* __restrict__ pooled,
               const float* __restrict__ w1, const float* __restrict__ b1,
               const float* __restrict__ w2, const float* __restrict__ b2,
               const float* __restrict__ w3, const float* __restrict__ b3,
               float* __restrict__ out)
{
    const int g = blockIdx.x, t = threadIdx.x;
    __shared__ float P[302], T1[100], T2[100];
    for (int i = t; i < 302; i += 128) P[i] = pooled[g * 302 + i];
    __syncthreads();
    if (t < 100) {
        float a = b1[t];
        for (int i = 0; i < 302; ++i) a = fmaf(P[i], w1[i * 100 + t], a);
        T1[t] = fmaxf(a, 0.f);
    }
    __syncthreads();
    if (t < 100) {
        float a = b2[t];
        for (int i = 0; i < 100; ++i) a = fmaf(T1[i], w2[i * 100 + t], a);
        T2[t] = fmaxf(a, 0.f);
    }
    __syncthreads();
    if (t < 2) {
        float a = b3[t];
        for (int i = 0; i < 100; ++i) a = fmaf(T2[i], w3[i * 2 + t], a);
        out[g * 2 + t] = a;
    }
}

// ---------------------------------------------------------------------------
extern "C" void kernel_launch(void* const* d_in, const int* in_sizes, int n_in,
                              void* d_out, int out_size, void* d_ws, size_t ws_size,
                              hipStream_t stream)
{
    const float* x     = (const float*)d_in[0];
    const int*   ei    = (const int*)d_in[1];
    const int*   batch = (const int*)d_in[2];
    const float* uu    = (const float*)d_in[3];
    const float *l0w1 = (const float*)d_in[4],  *l0b1 = (const float*)d_in[5];
    const float *l0w2 = (const float*)d_in[6],  *l0b2 = (const float*)d_in[7];
    const float *l0w3 = (const float*)d_in[8],  *l0b3 = (const float*)d_in[9];
    const float *l1w1 = (const float*)d_in[10], *l1b1 = (const float*)d_in[11];
    const float *l1w2 = (const float*)d_in[12], *l1b2 = (const float*)d_in[13];
    const float *l1w3 = (const float*)d_in[14], *l1b3 = (const float*)d_in[15];
    const float *lw1  = (const float*)d_in[16], *lb1  = (const float*)d_in[17];
    const float *lw2  = (const float*)d_in[18], *lb2  = (const float*)d_in[19];
    const float *lw3  = (const float*)d_in[20], *lb3  = (const float*)d_in[21];

    char* w = (char*)d_ws;
    float* agg0   = (float*)(w);                    //  20,000,000 B
    float* agg1   = (float*)(w + 20000000);         //  20,000,000 B
    float* pooled = (float*)(w + 40000000);         //      77,312 B
    u16* wtu0 = (u16*)(w + 40077312);               //      38,912 B
    u16* wtu1 = (u16*)(w + 40116224);               //     155,648 B
    u16* wt2a = (u16*)(w + 40271872);               //     204,800 B
    u16* wt2b = (u16*)(w + 40476672);               //     204,800 B
    u16* wt3a = (u16*)(w + 40681472);               //      71,680 B
    u16* wt3b = (u16*)(w + 40753152);               //      71,680 B
    int* hist = (int*)(w + 40824832);               //     200,000 B (run ends)
    int* sei  = (int*)(w + 41024832);               //   3,200,000 B (sorted)
    u16* msg  = (u16*)(w + 44224832);               //  89,600,000 B (224B rows)
    u16* UVb  = (u16*)(w + 133824832);              //  60,800,000 B (N x 608 bf16)
                                                    // total ~185.6 MiB

    ModelGNN_35304631174019_kernel<<<1509, 256, 0, stream>>>(
        l0w1, l0w2, l0w3, l1w1, l1w2, l1w3,
        l0b1, l0b2, l0b3, l1b1, l1b2, l1b3,
        (float4*)hist, wtu0, wtu1, wt2a, wt2b, wt3a, wt3b);
    hist_k<<<1563, 256, 0, stream>>>(ei, hist);
    scan_k<<<1, 1024, 0, stream>>>(hist);
    fill_k<<<1563, 256, 0, stream>>>(ei, hist, sei);
    gemm_uv<1><<<391, 256, 0, stream>>>(x, wtu0, UVb);
    edge_uv<<<3125, 256, 0, stream>>>(UVb, sei, wt2a, wt3a, msg);
    reduce_k<<<12500, 256, 0, stream>>>(msg, hist, agg0);
    gemm_uv<4><<<391, 256, 0, stream>>>(agg0, wtu1, UVb);
    edge_uv<<<3125, 256, 0, stream>>>(UVb, sei, wt2b, wt3b, msg);
    reduce_k<<<12500, 256, 0, stream>>>(msg, hist, agg1);
    pool<<<G_, 256, 0, stream>>>(agg1, batch, uu, pooled);
    final_mlp<<<G_, 128, 0, stream>>>(pooled, lw1, lb1, lw2, lb2, lw3, lb3, (float*)d_out);
}